// Round 6
// baseline (200.719 us; speedup 1.0000x reference)
//
#include <hip/hip_runtime.h>
#include <hip/hip_bf16.h>

#define B_ 8
#define N_ 1024
#define F_ 256
#define OUT_ 256
#define REL_ 16
#define NADJ_ 7

typedef __attribute__((ext_vector_type(8))) _Float16 f16x8;
typedef __attribute__((ext_vector_type(4))) _Float16 f16x4;
typedef __attribute__((ext_vector_type(4))) float f32x4;

__device__ __forceinline__ void gll16(const _Float16* g, _Float16* l) {
    __builtin_amdgcn_global_load_lds(
        (const __attribute__((address_space(1))) void*)g,
        (__attribute__((address_space(3))) void*)l, 16, 0, 0);
}

__device__ __forceinline__ f16x8 cvt8(float4 a, float4 b) {
    return f16x8{(_Float16)a.x, (_Float16)a.y, (_Float16)a.z, (_Float16)a.w,
                 (_Float16)b.x, (_Float16)b.y, (_Float16)b.z, (_Float16)b.w};
}

#define MEMPIN() asm volatile("" ::: "memory")

// perm order: rr 0..3 = r{0,1,3,4} (real adjacency), 4..6 = r{2,5,6} (identity adjacency)
__constant__ const int c_perm[7] = {0, 1, 3, 4, 2, 5, 6};

// ---------------- prep: cbias (blocks 0..6) | transW (7..1798) | cvt feat (1799..2822) ---
__global__ __launch_bounds__(256) void prep_kernel(const float* __restrict__ W,
                                                   const float* __restrict__ We,
                                                   const float* __restrict__ feat,
                                                   float* __restrict__ cb,
                                                   _Float16* __restrict__ WTp,
                                                   _Float16* __restrict__ Fe) {
    int bid = blockIdx.x, tid = threadIdx.x;
    if (bid < 7) {
        int idx = bid * 256 + tid;
        int j = idx / OUT_, o = idx % OUT_;
        int r = c_perm[j];
        const float* Wr = W + (size_t)r * (F_ + REL_) * OUT_;
        float s = 0.f;
#pragma unroll
        for (int d = 0; d < REL_; ++d) s += We[r * REL_ + d] * Wr[(F_ + d) * OUT_ + o];
        cb[idx] = s;
    } else if (bid < 1799) {
        int idx = (bid - 7) * 256 + tid;  // 7*65536 total
        int j = idx >> 16, rem = idx & 65535, o = rem >> 8, f = rem & 255;
        int r = c_perm[j];
        WTp[idx] = (_Float16)W[((size_t)r * (F_ + REL_) + f) * OUT_ + o];
    } else {
        int i = (bid - 1799) * 256 + tid;  // 262144 groups of 8
        size_t base = (size_t)i * 8;
        float4 a = *(const float4*)(feat + base);
        float4 b = *(const float4*)(feat + base + 4);
        *(f16x8*)(Fe + base) = cvt8(a, b);
    }
}

// ======= hw7: 7 HW GEMMs, 3-stage pipelined gll16 staging (round-5, verified).
// z<4: HWT[z][o][m] = (Fe @ W[z])^T + cb ; z>=4: HWN[z-4][m][o] = Fe @ W[z] + cb.
__global__ __launch_bounds__(256) void hw7_kernel(const _Float16* __restrict__ Fe,
                                                  const _Float16* __restrict__ WTp,
                                                  const float* __restrict__ cb,
                                                  _Float16* __restrict__ HWT,
                                                  _Float16* __restrict__ HWN) {
    __shared__ _Float16 S[3 * 8192];  // stage st: As = S+st*8192, Bs = As+4096 (BK=32)
    const int bid = blockIdx.x, tid = threadIdx.x;
    const int z = bid / 128, rem = bid % 128, bx = rem & 63, by = rem >> 6;
    const bool tr = (z < 4);
    const _Float16* A  = tr ? (WTp + (size_t)z * 65536) : Fe;
    const _Float16* Bt = tr ? Fe : (WTp + (size_t)z * 65536);
    const int m0 = (tr ? by : bx) * 128;
    const int n0 = (tr ? bx : by) * 128;
    const int wave = tid >> 6, lane = tid & 63, lm = lane & 15, q = lane >> 4;
    const int wr = (wave >> 1) * 64, wc = (wave & 1) * 64;
    const int srow = tid >> 2, sk = (tid & 3) * 8;
    const _Float16* ga0 = A + (size_t)(m0 + srow) * F_ + sk;
    const _Float16* ga1 = ga0 + (size_t)64 * F_;
    const _Float16* gb0 = Bt + (size_t)(n0 + srow) * F_ + sk;
    const _Float16* gb1 = gb0 + (size_t)64 * F_;

    f32x4 acc[4][4] = {};
    const int NT = 8;

    {
        gll16(ga0, S + tid * 8);
        gll16(ga1, S + 2048 + tid * 8);
        gll16(gb0, S + 4096 + tid * 8);
        gll16(gb1, S + 6144 + tid * 8);
        MEMPIN();
        gll16(ga0 + 32, S + 8192 + tid * 8);
        gll16(ga1 + 32, S + 8192 + 2048 + tid * 8);
        gll16(gb0 + 32, S + 8192 + 4096 + tid * 8);
        gll16(gb1 + 32, S + 8192 + 6144 + tid * 8);
        asm volatile("s_waitcnt vmcnt(4)" ::: "memory");  // stage-0 landed (mine)
        __builtin_amdgcn_s_barrier();
    }
    int cs = 0, ns = 1, fs = 2;
    for (int t = 0; t < NT; ++t) {
        if (t + 2 < NT) {
            const int k = (t + 2) * 32;
            _Float16* sb = S + fs * 8192;
            gll16(ga0 + k, sb + tid * 8);
            gll16(ga1 + k, sb + 2048 + tid * 8);
            gll16(gb0 + k, sb + 4096 + tid * 8);
            gll16(gb1 + k, sb + 6144 + tid * 8);
        }
        {
            const _Float16* Au = S + cs * 8192;
            const _Float16* Bu = Au + 4096;
            f16x8 af[4], bf[4];
#pragma unroll
            for (int i = 0; i < 4; ++i) af[i] = *(const f16x8*)(Au + (wr + i * 16 + lm) * 32 + q * 8);
#pragma unroll
            for (int j = 0; j < 4; ++j) bf[j] = *(const f16x8*)(Bu + (wc + j * 16 + lm) * 32 + q * 8);
            __builtin_amdgcn_s_setprio(1);
#pragma unroll
            for (int i = 0; i < 4; ++i)
#pragma unroll
                for (int j = 0; j < 4; ++j)
                    acc[i][j] = __builtin_amdgcn_mfma_f32_16x16x32_f16(af[i], bf[j], acc[i][j], 0, 0, 0);
            __builtin_amdgcn_s_setprio(0);
        }
        if (t + 1 < NT) {
            if (t + 2 < NT) asm volatile("s_waitcnt vmcnt(4)" ::: "memory");
            else            asm volatile("s_waitcnt vmcnt(0)" ::: "memory");
            __builtin_amdgcn_s_barrier();
        }
        int tmp = cs; cs = ns; ns = fs; fs = tmp;
    }
    const float* cbz = cb + (size_t)z * 256;
    if (tr) {
        _Float16* C = HWT + (size_t)z * ((size_t)256 * 8192);
#pragma unroll
        for (int i = 0; i < 4; ++i)
#pragma unroll
            for (int j = 0; j < 4; ++j)
#pragma unroll
                for (int g = 0; g < 4; ++g) {
                    int row = wr + i * 16 + q * 4 + g;   // o
                    int col = wc + j * 16 + lm;          // m
                    float v = acc[i][j][g] + cbz[m0 + row];
                    C[(size_t)(m0 + row) * 8192 + (n0 + col)] = (_Float16)v;
                }
    } else {
        _Float16* C = HWN + (size_t)(z - 4) * ((size_t)8192 * 256);
#pragma unroll
        for (int i = 0; i < 4; ++i)
#pragma unroll
            for (int j = 0; j < 4; ++j)
#pragma unroll
                for (int g = 0; g < 4; ++g) {
                    int row = wr + i * 16 + q * 4 + g;   // m
                    int col = wc + j * 16 + lm;          // o
                    float v = acc[i][j][g] + cbz[n0 + col];
                    C[(size_t)(m0 + row) * 256 + (n0 + col)] = (_Float16)v;
                }
    }
}

// ======= phase2: AHW[kh][rr][b][n][o] partial = A_rr[b][k-half] @ HWT-half^T =======
// Grid 1024 (K-split x2). B operand: DIRECT global b128 loads from HWT (L2-resident
// strip, no LDS). rr<2: A direct fp32 loads + cvt -> NO LDS, NO barriers at all.
// rr>=2: A^T via LDS [128 m][64 k] f16, 2-stage dbuf, BK=64 -> 8 barriers total,
// lane-spreading XOR swizzle s(r)=(r&7)^((r>>4)&7) on 16B granules (row stride 128B
// = bank-aligned rows; reads ~conflict-free, writes ~4-way). LDS written from regs,
// so lgkmcnt(0)+s_barrier fully orders it — no vmcnt asm anywhere.
// XCD remap: b == xcd (A slabs + B strips L2-pinned per XCD).
__global__ __launch_bounds__(256) void p2_kernel(const float* __restrict__ A1,
                                                 const float* __restrict__ A2,
                                                 const _Float16* __restrict__ HWT,
                                                 _Float16* __restrict__ AHW) {
    __shared__ _Float16 As[2 * 8192];   // 32 KB, used only by rr>=2 blocks
    const int d = blockIdx.x;
    const int xcd = d & 7, slot = d >> 3;
    const int mt = slot & 7;                 // m-tile
    const int member = (slot >> 3) & 1;      // o-tile
    const int kh = (slot >> 4) & 1;          // K half
    const int rr = slot >> 5;                // 0..3
    const int b = xcd;

    const size_t slab = (size_t)B_ * N_ * OUT_;
    const _Float16* Bt = HWT + (size_t)rr * (256 * 8192) + (size_t)b * 1024;
    _Float16* C = AHW + (size_t)kh * (4 * slab) + (size_t)rr * slab + (size_t)b * (N_ * OUT_);
    const int m0 = mt * 128, n0 = member * 128, kbase = kh * 512;
    const int tid = threadIdx.x;
    const int wave = tid >> 6, lane = tid & 63, lm = lane & 15, q = lane >> 4;
    const int wr = (wave >> 1) * 64, wc = (wave & 1) * 64;

    const float* Ag = ((rr & 1) ? A2 : A1) + (size_t)b * N_ * N_;
    f32x4 acc[4][4] = {};

    // B row pointers (direct global fragments): row o = n0+wc+j*16+lm, k = kbase+q*8+...
    const _Float16* brow[4];
#pragma unroll
    for (int j = 0; j < 4; ++j)
        brow[j] = Bt + (size_t)(n0 + wc + j * 16 + lm) * 8192 + kbase + q * 8;

    if (rr < 2) {
        // ---- straight: no LDS, no barriers; af direct from fp32 A + cvt ----
        const float* arow[4];
#pragma unroll
        for (int i = 0; i < 4; ++i)
            arow[i] = Ag + (size_t)(m0 + wr + i * 16 + lm) * N_ + kbase + q * 8;

        float4 a0[4][2];
        f16x8 b0[4];
#pragma unroll
        for (int i = 0; i < 4; ++i) {
            a0[i][0] = *(const float4*)(arow[i]);
            a0[i][1] = *(const float4*)(arow[i] + 4);
        }
#pragma unroll
        for (int j = 0; j < 4; ++j) b0[j] = *(const f16x8*)(brow[j]);
#pragma unroll
        for (int t = 0; t < 16; ++t) {
            float4 a1[4][2];
            f16x8 b1[4];
            if (t < 15) {
#pragma unroll
                for (int i = 0; i < 4; ++i) {
                    a1[i][0] = *(const float4*)(arow[i] + (t + 1) * 32);
                    a1[i][1] = *(const float4*)(arow[i] + (t + 1) * 32 + 4);
                }
#pragma unroll
                for (int j = 0; j < 4; ++j) b1[j] = *(const f16x8*)(brow[j] + (t + 1) * 32);
            }
            f16x8 af[4];
#pragma unroll
            for (int i = 0; i < 4; ++i) af[i] = cvt8(a0[i][0], a0[i][1]);
            __builtin_amdgcn_s_setprio(1);
#pragma unroll
            for (int i = 0; i < 4; ++i)
#pragma unroll
                for (int j = 0; j < 4; ++j)
                    acc[i][j] = __builtin_amdgcn_mfma_f32_16x16x32_f16(af[i], b0[j], acc[i][j], 0, 0, 0);
            __builtin_amdgcn_s_setprio(0);
            if (t < 15) {
#pragma unroll
                for (int i = 0; i < 4; ++i) { a0[i][0] = a1[i][0]; a0[i][1] = a1[i][1]; }
#pragma unroll
                for (int j = 0; j < 4; ++j) b0[j] = b1[j];
            }
        }
    } else {
        // ---- transposed: A^T via LDS [128][64], 2-stage, BK=64, 8 iters ----
        // thread reads k-rows lk..lk+3 (local), m-cols mc8..mc8+7
        const int lk = (tid >> 4) * 4, mc8 = (tid & 15) * 8;
        const int shi = (tid & 15) >> 1;     // (r>>4)&7 for rows mc8..mc8+7
        const float* gA = Ag + (size_t)(kbase + lk) * N_ + m0 + mc8;
        f32x4 rlo[4], rhi[4];

        auto RD = [&](int t) {
            const float* p = gA + (size_t)t * 64 * N_;
#pragma unroll
            for (int k = 0; k < 4; ++k) {
                rlo[k] = *(const f32x4*)(p + (size_t)k * N_);
                rhi[k] = *(const f32x4*)(p + (size_t)k * N_ + 4);
            }
        };
        auto WRS = [&](int st) {
            _Float16* base = As + st * 8192;
            const int g0 = lk >> 3, kof = lk & 7;
#pragma unroll
            for (int c = 0; c < 4; ++c) {
                int r = mc8 + c, s = c ^ shi;
                *(f16x4*)(base + r * 64 + ((g0 ^ s) << 3) + kof) =
                    f16x4{(_Float16)rlo[0][c], (_Float16)rlo[1][c], (_Float16)rlo[2][c], (_Float16)rlo[3][c]};
            }
#pragma unroll
            for (int c = 0; c < 4; ++c) {
                int r = mc8 + 4 + c, s = (4 + c) ^ shi;
                *(f16x4*)(base + r * 64 + ((g0 ^ s) << 3) + kof) =
                    f16x4{(_Float16)rhi[0][c], (_Float16)rhi[1][c], (_Float16)rhi[2][c], (_Float16)rhi[3][c]};
            }
        };

        RD(0);
        WRS(0);
        RD(1);
        asm volatile("s_waitcnt lgkmcnt(0)" ::: "memory");
        __builtin_amdgcn_s_barrier();

#pragma unroll
        for (int t = 0; t < 8; ++t) {
            const int cs = t & 1, ns = cs ^ 1;
            if (t < 7) WRS(ns);
            if (t < 6) RD(t + 2);
#pragma unroll
            for (int h = 0; h < 2; ++h) {
                f16x8 af[4], bf[4];
#pragma unroll
                for (int i = 0; i < 4; ++i) {
                    int r = wr + i * 16 + lm;
                    int s = (lm & 7) ^ (((wr >> 4) + i) & 7);
                    af[i] = *(const f16x8*)(As + cs * 8192 + r * 64 + (((h * 4 + q) ^ s) << 3));
                }
#pragma unroll
                for (int j = 0; j < 4; ++j) bf[j] = *(const f16x8*)(brow[j] + t * 64 + h * 32);
                __builtin_amdgcn_s_setprio(1);
#pragma unroll
                for (int i = 0; i < 4; ++i)
#pragma unroll
                    for (int j = 0; j < 4; ++j)
                        acc[i][j] = __builtin_amdgcn_mfma_f32_16x16x32_f16(af[i], bf[j], acc[i][j], 0, 0, 0);
                __builtin_amdgcn_s_setprio(0);
            }
            asm volatile("s_waitcnt lgkmcnt(0)" ::: "memory");
            __builtin_amdgcn_s_barrier();
        }
    }
#pragma unroll
    for (int i = 0; i < 4; ++i)
#pragma unroll
        for (int j = 0; j < 4; ++j)
#pragma unroll
            for (int g = 0; g < 4; ++g) {
                int row = wr + i * 16 + q * 4 + g;
                int col = wc + j * 16 + lm;
                C[(size_t)(m0 + row) * 256 + (n0 + col)] = (_Float16)acc[i][j][g];
            }
}

// ======= final: out = max over rr of (AHW_half0 + AHW_half1), max with HWN, + bias =======
__global__ __launch_bounds__(256) void max_kernel(const _Float16* __restrict__ AHW,
                                                  const _Float16* __restrict__ HWN,
                                                  const float* __restrict__ bias,
                                                  float* __restrict__ out) {
    size_t i = ((size_t)blockIdx.x * 256 + threadIdx.x) * 8;
    const size_t slab = (size_t)B_ * N_ * OUT_;
    const size_t HS = 4 * slab;
    float m[8];
    {
        f16x8 v0 = *(const f16x8*)(AHW + i);
        f16x8 v1 = *(const f16x8*)(AHW + HS + i);
#pragma unroll
        for (int e = 0; e < 8; ++e) m[e] = (float)v0[e] + (float)v1[e];
    }
#pragma unroll
    for (int rr = 1; rr < 4; ++rr) {
        f16x8 v0 = *(const f16x8*)(AHW + rr * slab + i);
        f16x8 v1 = *(const f16x8*)(AHW + HS + rr * slab + i);
#pragma unroll
        for (int e = 0; e < 8; ++e) m[e] = fmaxf(m[e], (float)v0[e] + (float)v1[e]);
    }
#pragma unroll
    for (int j = 0; j < 3; ++j) {
        f16x8 w = *(const f16x8*)(HWN + j * slab + i);
#pragma unroll
        for (int e = 0; e < 8; ++e) m[e] = fmaxf(m[e], (float)w[e]);
    }
    size_t bidx = i & ((size_t)N_ * OUT_ - 1);
    float4 b0 = *(const float4*)(bias + bidx);
    float4 b1 = *(const float4*)(bias + bidx + 4);
    float4 o0 = {m[0] + b0.x, m[1] + b0.y, m[2] + b0.z, m[3] + b0.w};
    float4 o1 = {m[4] + b1.x, m[5] + b1.y, m[6] + b1.z, m[7] + b1.w};
    *(float4*)(out + i) = o0;
    *(float4*)(out + i + 4) = o1;
}

// ======================= round-1 fallback path (ws too small) ===========================
__global__ void cbias_kernel(const float* __restrict__ W, const float* __restrict__ We,
                             float* __restrict__ c) {
    int idx = blockIdx.x * 256 + threadIdx.x;
    if (idx >= NADJ_ * OUT_) return;
    int r = idx / OUT_, o = idx % OUT_;
    const float* Wr = W + (size_t)r * (F_ + REL_) * OUT_;
    float s = 0.f;
#pragma unroll
    for (int d = 0; d < REL_; ++d) s += We[r * REL_ + d] * Wr[(F_ + d) * OUT_ + o];
    c[idx] = s;
}

__global__ __launch_bounds__(256) void hw_kernel(const float* __restrict__ feat,
                                                 const float* __restrict__ W,
                                                 const float* __restrict__ cb,
                                                 _Float16* __restrict__ HWb) {
    __shared__ _Float16 As[64][32];
    __shared__ _Float16 Bs[64][32];
    const int mt = blockIdx.x, ct = blockIdx.y;
    const int tid = threadIdx.x, wave = tid >> 6, lane = tid & 63;
    const int r = (ct * 64) / OUT_;
    const int o0 = (ct * 64) % OUT_;
    const float* Bg = W + (size_t)r * (F_ + REL_) * OUT_ + o0;
    const int m0 = mt * 64;
    const int lm = lane & 15, q = lane >> 4;
    f32x4 acc[4] = {};
    for (int k0 = 0; k0 < F_; k0 += 32) {
        {
            int seg = (tid & 3) * 8, m = tid >> 2;
            const float* src = feat + (size_t)(m0 + m) * F_ + k0 + seg;
#pragma unroll
            for (int j = 0; j < 8; ++j) As[m][seg + j] = (_Float16)src[j];
        }
        {
            int kk = tid >> 3, ns = (tid & 7) * 8;
            const float* src = Bg + (size_t)(k0 + kk) * OUT_ + ns;
#pragma unroll
            for (int j = 0; j < 8; ++j) Bs[ns + j][kk] = (_Float16)src[j];
        }
        __syncthreads();
        f16x8 a = *(const f16x8*)&As[wave * 16 + lm][q * 8];
#pragma unroll
        for (int c4 = 0; c4 < 4; ++c4) {
            f16x8 b = *(const f16x8*)&Bs[c4 * 16 + lm][q * 8];
            acc[c4] = __builtin_amdgcn_mfma_f32_16x16x32_f16(a, b, acc[c4], 0, 0, 0);
        }
        __syncthreads();
    }
#pragma unroll
    for (int c4 = 0; c4 < 4; ++c4)
#pragma unroll
        for (int g = 0; g < 4; ++g) {
            int row = wave * 16 + (lane >> 4) * 4 + g;
            int col = c4 * 16 + lm;
            float v = acc[c4][g] + cb[r * OUT_ + o0 + col];
            HWb[((size_t)r * B_ * N_ + m0 + row) * OUT_ + o0 + col] = (_Float16)v;
        }
}

__global__ __launch_bounds__(256) void agg_kernel(const float* __restrict__ A1,
                                                  const float* __restrict__ A2,
                                                  const _Float16* __restrict__ HWb,
                                                  const float* __restrict__ bias,
                                                  float* __restrict__ out) {
    __shared__ _Float16 As[64][32];
    __shared__ _Float16 Bs[64][32];
    const int b = blockIdx.z, nt = blockIdx.y, ot = blockIdx.x;
    const int tid = threadIdx.x, wave = tid >> 6, lane = tid & 63;
    const int n0 = nt * 64, o0 = ot * 64;
    const int lm = lane & 15, q = lane >> 4;
    const size_t rstride = (size_t)B_ * N_ * OUT_;
    f32x4 mx[4];
#pragma unroll
    for (int i = 0; i < 4; ++i) mx[i] = f32x4{-1e30f, -1e30f, -1e30f, -1e30f};
#pragma unroll 1
    for (int rr = 0; rr < 4; ++rr) {
        const float* Ag = ((rr & 1) ? A2 : A1) + (size_t)b * N_ * N_;
        const bool tr = (rr >= 2);
        const int r = (rr < 2) ? rr : rr + 1;
        const _Float16* Bg = HWb + (size_t)r * rstride + (size_t)b * N_ * OUT_ + o0;
        f32x4 acc[4] = {};
        for (int k0 = 0; k0 < N_; k0 += 32) {
            if (!tr) {
                int seg = (tid & 3) * 8, m = tid >> 2;
                const float* src = Ag + (size_t)(n0 + m) * N_ + k0 + seg;
#pragma unroll
                for (int j = 0; j < 8; ++j) As[m][seg + j] = (_Float16)src[j];
            } else {
                int kk = tid >> 3, ms = (tid & 7) * 8;
                const float* src = Ag + (size_t)(k0 + kk) * N_ + n0 + ms;
#pragma unroll
                for (int j = 0; j < 8; ++j) As[ms + j][kk] = (_Float16)src[j];
            }
            {
                int kk = tid >> 3, ns = (tid & 7) * 8;
                const _Float16* src = Bg + (size_t)(k0 + kk) * OUT_ + ns;
#pragma unroll
                for (int j = 0; j < 8; ++j) Bs[ns + j][kk] = src[j];
            }
            __syncthreads();
            f16x8 a = *(const f16x8*)&As[wave * 16 + lm][q * 8];
#pragma unroll
            for (int c4 = 0; c4 < 4; ++c4) {
                f16x8 bb = *(const f16x8*)&Bs[c4 * 16 + lm][q * 8];
                acc[c4] = __builtin_amdgcn_mfma_f32_16x16x32_f16(a, bb, acc[c4], 0, 0, 0);
            }
            __syncthreads();
        }
#pragma unroll
        for (int c4 = 0; c4 < 4; ++c4)
#pragma unroll
            for (int g = 0; g < 4; ++g) mx[c4][g] = fmaxf(mx[c4][g], acc[c4][g]);
    }
#pragma unroll
    for (int c4 = 0; c4 < 4; ++c4)
#pragma unroll
        for (int g = 0; g < 4; ++g) {
            int row = wave * 16 + (lane >> 4) * 4 + g;
            int col = c4 * 16 + lm;
            size_t pos = ((size_t)b * N_ + n0 + row) * OUT_ + o0 + col;
            float v = mx[c4][g];
            v = fmaxf(v, (float)HWb[2 * rstride + pos]);
            v = fmaxf(v, (float)HWb[5 * rstride + pos]);
            v = fmaxf(v, (float)HWb[6 * rstride + pos]);
            out[pos] = v + bias[((size_t)(n0 + row)) * OUT_ + o0 + col];
        }
}

// ========================================================================================
extern "C" void kernel_launch(void* const* d_in, const int* in_sizes, int n_in,
                              void* d_out, int out_size, void* d_ws, size_t ws_size,
                              hipStream_t stream) {
    const float* feat = (const float*)d_in[0];
    const float* A1   = (const float*)d_in[1];
    const float* A2   = (const float*)d_in[2];
    const float* W    = (const float*)d_in[3];
    const float* We   = (const float*)d_in[4];
    const float* bias = (const float*)d_in[5];
    float* out = (float*)d_out;

    // fast-path ws layout (bytes) — AHW 2 K-halves x 16 MB, total 65 MB
    const size_t OFF_CB   = 0;          //   8 KB
    const size_t OFF_WT   = 8192;       // 896 KB
    const size_t OFF_FE   = 1048576;    //   4 MB
    const size_t OFF_HWT  = 5242880;    //  16 MB
    const size_t OFF_HWN  = 22020096;   //  12 MB
    const size_t OFF_AHW  = 34603008;   //  32 MB (2 halves)
    const size_t WS_NEEDED = 68157440;

    if (ws_size >= WS_NEEDED) {
        float*    cbp = (float*)((char*)d_ws + OFF_CB);
        _Float16* WTp = (_Float16*)((char*)d_ws + OFF_WT);
        _Float16* Fe  = (_Float16*)((char*)d_ws + OFF_FE);
        _Float16* HWT = (_Float16*)((char*)d_ws + OFF_HWT);
        _Float16* HWN = (_Float16*)((char*)d_ws + OFF_HWN);
        _Float16* AHW = (_Float16*)((char*)d_ws + OFF_AHW);

        prep_kernel<<<2823, 256, 0, stream>>>(W, We, feat, cbp, WTp, Fe);
        hw7_kernel<<<896, 256, 0, stream>>>(Fe, WTp, cbp, HWT, HWN);
        p2_kernel<<<1024, 256, 0, stream>>>(A1, A2, HWT, AHW);
        max_kernel<<<1024, 256, 0, stream>>>(AHW, HWN, bias, out);
    } else {
        // round-1 fallback
        float* cb = (float*)d_ws;
        _Float16* HWb = (_Float16*)((char*)d_ws + 8192);
        cbias_kernel<<<7, 256, 0, stream>>>(W, We, cb);
        hw_kernel<<<dim3(128, 28), 256, 0, stream>>>(feat, W, cb, HWb);
        agg_kernel<<<dim3(4, 16, 8), 256, 0, stream>>>(A1, A2, HWb, bias, out);
    }
}

// Round 7
// 167.462 us; speedup vs baseline: 1.1986x; 1.1986x over previous
//
#include <hip/hip_runtime.h>
#include <hip/hip_bf16.h>

#define B_ 8
#define N_ 1024
#define F_ 256
#define OUT_ 256
#define REL_ 16
#define NADJ_ 7

typedef __attribute__((ext_vector_type(8))) _Float16 f16x8;
typedef __attribute__((ext_vector_type(4))) _Float16 f16x4;
typedef __attribute__((ext_vector_type(4))) float f32x4;

__device__ __forceinline__ void gll16(const _Float16* g, _Float16* l) {
    __builtin_amdgcn_global_load_lds(
        (const __attribute__((address_space(1))) void*)g,
        (__attribute__((address_space(3))) void*)l, 16, 0, 0);
}

__device__ __forceinline__ f16x8 cvt8(float4 a, float4 b) {
    return f16x8{(_Float16)a.x, (_Float16)a.y, (_Float16)a.z, (_Float16)a.w,
                 (_Float16)b.x, (_Float16)b.y, (_Float16)b.z, (_Float16)b.w};
}

#define MEMPIN() asm volatile("" ::: "memory")

// perm order: rr 0..3 = r{0,1,3,4} (real adjacency), 4..6 = r{2,5,6} (identity adjacency)
__constant__ const int c_perm[7] = {0, 1, 3, 4, 2, 5, 6};

// ---------------- prep: cbias (blocks 0..6) | transW (7..1798) | cvt feat (1799..2822) ---
__global__ __launch_bounds__(256) void prep_kernel(const float* __restrict__ W,
                                                   const float* __restrict__ We,
                                                   const float* __restrict__ feat,
                                                   float* __restrict__ cb,
                                                   _Float16* __restrict__ WTp,
                                                   _Float16* __restrict__ Fe) {
    int bid = blockIdx.x, tid = threadIdx.x;
    if (bid < 7) {
        int idx = bid * 256 + tid;
        int j = idx / OUT_, o = idx % OUT_;
        int r = c_perm[j];
        const float* Wr = W + (size_t)r * (F_ + REL_) * OUT_;
        float s = 0.f;
#pragma unroll
        for (int d = 0; d < REL_; ++d) s += We[r * REL_ + d] * Wr[(F_ + d) * OUT_ + o];
        cb[idx] = s;
    } else if (bid < 1799) {
        int idx = (bid - 7) * 256 + tid;  // 7*65536 total
        int j = idx >> 16, rem = idx & 65535, o = rem >> 8, f = rem & 255;
        int r = c_perm[j];
        WTp[idx] = (_Float16)W[((size_t)r * (F_ + REL_) + f) * OUT_ + o];
    } else {
        int i = (bid - 1799) * 256 + tid;  // 262144 groups of 8
        size_t base = (size_t)i * 8;
        float4 a = *(const float4*)(feat + base);
        float4 b = *(const float4*)(feat + base + 4);
        *(f16x8*)(Fe + base) = cvt8(a, b);
    }
}

// ======= hw7: 7 HW GEMMs, 3-stage pipelined gll16 staging (round-5, verified).
// z<4: HWT[z][b][o][m_local] = (Fe @ W[z])^T + cb  (NEW per-batch-contiguous layout;
//      p2's B strip becomes a compact 512 KB region) ;
// z>=4: HWN[z-4][m][o] = Fe @ W[z] + cb.
__global__ __launch_bounds__(256) void hw7_kernel(const _Float16* __restrict__ Fe,
                                                  const _Float16* __restrict__ WTp,
                                                  const float* __restrict__ cb,
                                                  _Float16* __restrict__ HWT,
                                                  _Float16* __restrict__ HWN) {
    __shared__ _Float16 S[3 * 8192];  // stage st: As = S+st*8192, Bs = As+4096 (BK=32)
    const int bid = blockIdx.x, tid = threadIdx.x;
    const int z = bid / 128, rem = bid % 128, bx = rem & 63, by = rem >> 6;
    const bool tr = (z < 4);
    const _Float16* A  = tr ? (WTp + (size_t)z * 65536) : Fe;
    const _Float16* Bt = tr ? Fe : (WTp + (size_t)z * 65536);
    const int m0 = (tr ? by : bx) * 128;
    const int n0 = (tr ? bx : by) * 128;
    const int wave = tid >> 6, lane = tid & 63, lm = lane & 15, q = lane >> 4;
    const int wr = (wave >> 1) * 64, wc = (wave & 1) * 64;
    const int srow = tid >> 2, sk = (tid & 3) * 8;
    const _Float16* ga0 = A + (size_t)(m0 + srow) * F_ + sk;
    const _Float16* ga1 = ga0 + (size_t)64 * F_;
    const _Float16* gb0 = Bt + (size_t)(n0 + srow) * F_ + sk;
    const _Float16* gb1 = gb0 + (size_t)64 * F_;

    f32x4 acc[4][4] = {};
    const int NT = 8;

    {
        gll16(ga0, S + tid * 8);
        gll16(ga1, S + 2048 + tid * 8);
        gll16(gb0, S + 4096 + tid * 8);
        gll16(gb1, S + 6144 + tid * 8);
        MEMPIN();
        gll16(ga0 + 32, S + 8192 + tid * 8);
        gll16(ga1 + 32, S + 8192 + 2048 + tid * 8);
        gll16(gb0 + 32, S + 8192 + 4096 + tid * 8);
        gll16(gb1 + 32, S + 8192 + 6144 + tid * 8);
        asm volatile("s_waitcnt vmcnt(4)" ::: "memory");  // stage-0 landed (mine)
        __builtin_amdgcn_s_barrier();
    }
    int cs = 0, ns = 1, fs = 2;
    for (int t = 0; t < NT; ++t) {
        if (t + 2 < NT) {
            const int k = (t + 2) * 32;
            _Float16* sb = S + fs * 8192;
            gll16(ga0 + k, sb + tid * 8);
            gll16(ga1 + k, sb + 2048 + tid * 8);
            gll16(gb0 + k, sb + 4096 + tid * 8);
            gll16(gb1 + k, sb + 6144 + tid * 8);
        }
        {
            const _Float16* Au = S + cs * 8192;
            const _Float16* Bu = Au + 4096;
            f16x8 af[4], bf[4];
#pragma unroll
            for (int i = 0; i < 4; ++i) af[i] = *(const f16x8*)(Au + (wr + i * 16 + lm) * 32 + q * 8);
#pragma unroll
            for (int j = 0; j < 4; ++j) bf[j] = *(const f16x8*)(Bu + (wc + j * 16 + lm) * 32 + q * 8);
            __builtin_amdgcn_s_setprio(1);
#pragma unroll
            for (int i = 0; i < 4; ++i)
#pragma unroll
                for (int j = 0; j < 4; ++j)
                    acc[i][j] = __builtin_amdgcn_mfma_f32_16x16x32_f16(af[i], bf[j], acc[i][j], 0, 0, 0);
            __builtin_amdgcn_s_setprio(0);
        }
        if (t + 1 < NT) {
            if (t + 2 < NT) asm volatile("s_waitcnt vmcnt(4)" ::: "memory");
            else            asm volatile("s_waitcnt vmcnt(0)" ::: "memory");
            __builtin_amdgcn_s_barrier();
        }
        int tmp = cs; cs = ns; ns = fs; fs = tmp;
    }
    const float* cbz = cb + (size_t)z * 256;
    if (tr) {
        // NEW layout: HWT[z][b][o][m_local]; tile lies in one b (n0 = bx*128, 1024|b-span)
        _Float16* C = HWT + (size_t)z * (8 * 256 * 1024) + (size_t)(n0 >> 10) * (256 * 1024);
        const int nl = n0 & 1023;
#pragma unroll
        for (int i = 0; i < 4; ++i)
#pragma unroll
            for (int j = 0; j < 4; ++j)
#pragma unroll
                for (int g = 0; g < 4; ++g) {
                    int row = wr + i * 16 + q * 4 + g;   // o
                    int col = wc + j * 16 + lm;          // m_local
                    float v = acc[i][j][g] + cbz[m0 + row];
                    C[(size_t)(m0 + row) * 1024 + nl + col] = (_Float16)v;
                }
    } else {
        _Float16* C = HWN + (size_t)(z - 4) * ((size_t)8192 * 256);
#pragma unroll
        for (int i = 0; i < 4; ++i)
#pragma unroll
            for (int j = 0; j < 4; ++j)
#pragma unroll
                for (int g = 0; g < 4; ++g) {
                    int row = wr + i * 16 + q * 4 + g;   // m
                    int col = wc + j * 16 + lm;          // o
                    float v = acc[i][j][g] + cbz[n0 + col];
                    C[(size_t)(m0 + row) * 256 + (n0 + col)] = (_Float16)v;
                }
    }
}

// ======= phase2: AHW[kh][rr][b][n][o] partial = A_rr[b][k-half] @ HWT[rr][b]-half^T ====
// Round-2 structure (verified fastest) with: (a) full-BK64 double buffer -> ONE
// __syncthreads per 64-k iteration (8 barriers/block vs 16); (b) compact B strip
// (HWT[rr][b] contiguous 512 KB, row stride 1024). Grid 1024 (K-split x2), 4 blocks/CU.
// As layout per sub-tile: element (m,k) at [buf*8192 + sub*4096 + m*32 + (k ^ swz)].
__global__ __launch_bounds__(256) void p2_kernel(const float* __restrict__ A1,
                                                 const float* __restrict__ A2,
                                                 const _Float16* __restrict__ HWT,
                                                 _Float16* __restrict__ AHW) {
    __shared__ _Float16 As[2 * 8192];
    __shared__ _Float16 Bs[2 * 8192];
    const int d = blockIdx.x;
    const int xcd = d & 7, slot = d >> 3;
    const int Ghi = xcd + 8 * (slot >> 4);      // [0,64): (zz,kh) group
    const int member = (slot >> 3) & 1;         // o-tile
    const int mt = slot & 7;                    // m-tile
    const int kh = Ghi & 1;                     // K half
    const int zz = Ghi >> 1;                    // rr*8+b
    const int rr = zz >> 3, b = zz & 7;

    const size_t slab = (size_t)B_ * N_ * OUT_;
    const _Float16* Bt = HWT + (size_t)(rr * 8 + b) * (256 * 1024);
    _Float16* C = AHW + (size_t)kh * (4 * slab) + (size_t)rr * slab + (size_t)b * (N_ * OUT_);
    const int m0 = mt * 128, n0 = member * 128, kbase = kh * 512;
    const int tid = threadIdx.x;
    const int wave = tid >> 6, lane = tid & 63, lm = lane & 15, q = lane >> 4;
    const int wr = (wave >> 1) * 64, wc = (wave & 1) * 64;
    const int srow = tid >> 2, sk = (tid & 3) * 8;
    const _Float16* gb0 = Bt + (size_t)(n0 + srow) * 1024 + kbase + sk;
    const _Float16* gb1 = gb0 + (size_t)64 * 1024;

    const float* Ag = ((rr & 1) ? A2 : A1) + (size_t)b * N_ * N_;
    f32x4 acc[4][4] = {};

    auto domfma = [&](int buf) {
#pragma unroll
        for (int u2 = 0; u2 < 2; ++u2) {
            const _Float16* Au = As + buf * 8192 + u2 * 4096;
            const _Float16* Bu = Bs + buf * 8192 + u2 * 4096;
            f16x8 af[4], bf[4];
#pragma unroll
            for (int i = 0; i < 4; ++i)
                af[i] = *(const f16x8*)(Au + (wr + i * 16 + lm) * 32 + ((q ^ i) * 8));
#pragma unroll
            for (int j = 0; j < 4; ++j)
                bf[j] = *(const f16x8*)(Bu + (wc + j * 16 + lm) * 32 + q * 8);
            __builtin_amdgcn_s_setprio(1);
#pragma unroll
            for (int i = 0; i < 4; ++i)
#pragma unroll
                for (int j = 0; j < 4; ++j)
                    acc[i][j] = __builtin_amdgcn_mfma_f32_16x16x32_f16(af[i], bf[j], acc[i][j], 0, 0, 0);
            __builtin_amdgcn_s_setprio(0);
        }
    };

    auto stageB = [&](int buf, int k2) {  // stage 64 k (2 sub-tiles) of B into buf
        _Float16* base = Bs + buf * 8192;
        gll16(gb0 + k2,      base + tid * 8);          // sub0, rows 0..63
        gll16(gb0 + k2 + 32, base + 4096 + tid * 8);   // sub1, rows 0..63
        gll16(gb1 + k2,      base + 2048 + tid * 8);   // sub0, rows 64..127
        gll16(gb1 + k2 + 32, base + 6144 + tid * 8);   // sub1, rows 64..127
    };

    if (rr < 2) {
        // straight: As[m][k] = Ag[m0+m][kbase + t*64 + k]; regs hold next stage's 64 k
        const float* Ag0 = Ag + (size_t)(m0 + srow) * N_ + kbase + sk;
        const float* Ag1 = Ag0 + (size_t)64 * N_;
        const int sx = ((tid & 3) ^ ((tid >> 6) & 3)) * 8;
        float4 r0a, r0b, r1a, r1b, r2a, r2b, r3a, r3b;
        auto RDA = [&](int k2) {
            r0a = *(const float4*)(Ag0 + k2);      r0b = *(const float4*)(Ag0 + k2 + 4);
            r1a = *(const float4*)(Ag0 + k2 + 32); r1b = *(const float4*)(Ag0 + k2 + 36);
            r2a = *(const float4*)(Ag1 + k2);      r2b = *(const float4*)(Ag1 + k2 + 4);
            r3a = *(const float4*)(Ag1 + k2 + 32); r3b = *(const float4*)(Ag1 + k2 + 36);
        };
        auto WRA = [&](int buf) {
            _Float16* la = As + buf * 8192 + srow * 32 + sx;
            *(f16x8*)(la)        = cvt8(r0a, r0b);   // sub0, rows 0..63
            *(f16x8*)(la + 4096) = cvt8(r1a, r1b);   // sub1, rows 0..63
            *(f16x8*)(la + 2048) = cvt8(r2a, r2b);   // sub0, rows 64..127
            *(f16x8*)(la + 6144) = cvt8(r3a, r3b);   // sub1, rows 64..127
        };
        RDA(0);
        WRA(0);
        stageB(0, 0);
        RDA(64);
        __syncthreads();
        for (int t = 0; t < 8; ++t) {
            const int cur = t & 1, nxt = cur ^ 1;
            if (t < 7) {
                WRA(nxt);
                stageB(nxt, (t + 1) * 64);
                if (t < 6) RDA((t + 2) * 64);
            }
            domfma(cur);
            __syncthreads();
        }
    } else {
        // transposed: As[m][k] = Ag[kbase + t*64 + kk4+i][m0+m]; coalesced k-row reads,
        // b64 scatter into swizzled LDS. Thread: k-rows kk4..+3, cols ms..ms+7.
        const int kk4 = (tid >> 4) * 4;          // 0..60 (covers both sub-tiles)
        const int ms = (tid & 15) * 8;
        const int u = kk4 >> 5, kl = kk4 & 31;
        const int tsw = ((ms >> 4) & 3) << 3;
        const int wof = u * 4096 + ms * 32 + (kl ^ tsw);
        const float* gA = Ag + (size_t)(kbase + kk4) * N_ + m0 + ms;
        float4 ra0, rb0, ra1, rb1, ra2, rb2, ra3, rb3;
        auto RDT = [&](int t) {
            const float* p = gA + (size_t)t * 64 * N_;
            ra0 = *(const float4*)(p);            rb0 = *(const float4*)(p + 4);
            ra1 = *(const float4*)(p + N_);       rb1 = *(const float4*)(p + N_ + 4);
            ra2 = *(const float4*)(p + 2 * N_);   rb2 = *(const float4*)(p + 2 * N_ + 4);
            ra3 = *(const float4*)(p + 3 * N_);   rb3 = *(const float4*)(p + 3 * N_ + 4);
        };
        auto WRT = [&](int buf) {
            _Float16* wp = As + buf * 8192 + wof;
            *(f16x4*)(wp + 0 * 32) = f16x4{(_Float16)ra0.x, (_Float16)ra1.x, (_Float16)ra2.x, (_Float16)ra3.x};
            *(f16x4*)(wp + 1 * 32) = f16x4{(_Float16)ra0.y, (_Float16)ra1.y, (_Float16)ra2.y, (_Float16)ra3.y};
            *(f16x4*)(wp + 2 * 32) = f16x4{(_Float16)ra0.z, (_Float16)ra1.z, (_Float16)ra2.z, (_Float16)ra3.z};
            *(f16x4*)(wp + 3 * 32) = f16x4{(_Float16)ra0.w, (_Float16)ra1.w, (_Float16)ra2.w, (_Float16)ra3.w};
            *(f16x4*)(wp + 4 * 32) = f16x4{(_Float16)rb0.x, (_Float16)rb1.x, (_Float16)rb2.x, (_Float16)rb3.x};
            *(f16x4*)(wp + 5 * 32) = f16x4{(_Float16)rb0.y, (_Float16)rb1.y, (_Float16)rb2.y, (_Float16)rb3.y};
            *(f16x4*)(wp + 6 * 32) = f16x4{(_Float16)rb0.z, (_Float16)rb1.z, (_Float16)rb2.z, (_Float16)rb3.z};
            *(f16x4*)(wp + 7 * 32) = f16x4{(_Float16)rb0.w, (_Float16)rb1.w, (_Float16)rb2.w, (_Float16)rb3.w};
        };
        RDT(0);
        WRT(0);
        stageB(0, 0);
        RDT(1);
        __syncthreads();
        for (int t = 0; t < 8; ++t) {
            const int cur = t & 1, nxt = cur ^ 1;
            if (t < 7) {
                WRT(nxt);
                stageB(nxt, (t + 1) * 64);
                if (t < 6) RDT(t + 2);
            }
            domfma(cur);
            __syncthreads();
        }
    }
#pragma unroll
    for (int i = 0; i < 4; ++i)
#pragma unroll
        for (int j = 0; j < 4; ++j)
#pragma unroll
            for (int g = 0; g < 4; ++g) {
                int row = wr + i * 16 + q * 4 + g;
                int col = wc + j * 16 + lm;
                C[(size_t)(m0 + row) * 256 + (n0 + col)] = (_Float16)acc[i][j][g];
            }
}

// ======= final: out = max over rr of (AHW_half0 + AHW_half1), max with HWN, + bias =======
__global__ __launch_bounds__(256) void max_kernel(const _Float16* __restrict__ AHW,
                                                  const _Float16* __restrict__ HWN,
                                                  const float* __restrict__ bias,
                                                  float* __restrict__ out) {
    size_t i = ((size_t)blockIdx.x * 256 + threadIdx.x) * 8;
    const size_t slab = (size_t)B_ * N_ * OUT_;
    const size_t HS = 4 * slab;
    float m[8];
    {
        f16x8 v0 = *(const f16x8*)(AHW + i);
        f16x8 v1 = *(const f16x8*)(AHW + HS + i);
#pragma unroll
        for (int e = 0; e < 8; ++e) m[e] = (float)v0[e] + (float)v1[e];
    }
#pragma unroll
    for (int rr = 1; rr < 4; ++rr) {
        f16x8 v0 = *(const f16x8*)(AHW + rr * slab + i);
        f16x8 v1 = *(const f16x8*)(AHW + HS + rr * slab + i);
#pragma unroll
        for (int e = 0; e < 8; ++e) m[e] = fmaxf(m[e], (float)v0[e] + (float)v1[e]);
    }
#pragma unroll
    for (int j = 0; j < 3; ++j) {
        f16x8 w = *(const f16x8*)(HWN + j * slab + i);
#pragma unroll
        for (int e = 0; e < 8; ++e) m[e] = fmaxf(m[e], (float)w[e]);
    }
    size_t bidx = i & ((size_t)N_ * OUT_ - 1);
    float4 b0 = *(const float4*)(bias + bidx);
    float4 b1 = *(const float4*)(bias + bidx + 4);
    float4 o0 = {m[0] + b0.x, m[1] + b0.y, m[2] + b0.z, m[3] + b0.w};
    float4 o1 = {m[4] + b1.x, m[5] + b1.y, m[6] + b1.z, m[7] + b1.w};
    *(float4*)(out + i) = o0;
    *(float4*)(out + i + 4) = o1;
}

// ======================= round-1 fallback path (ws too small) ===========================
__global__ void cbias_kernel(const float* __restrict__ W, const float* __restrict__ We,
                             float* __restrict__ c) {
    int idx = blockIdx.x * 256 + threadIdx.x;
    if (idx >= NADJ_ * OUT_) return;
    int r = idx / OUT_, o = idx % OUT_;
    const float* Wr = W + (size_t)r * (F_ + REL_) * OUT_;
    float s = 0.f;
#pragma unroll
    for (int d = 0; d < REL_; ++d) s += We[r * REL_ + d] * Wr[(F_ + d) * OUT_ + o];
    c[idx] = s;
}

__global__ __launch_bounds__(256) void hw_kernel(const float* __restrict__ feat,
                                                 const float* __restrict__ W,
                                                 const float* __restrict__ cb,
                                                 _Float16* __restrict__ HWb) {
    __shared__ _Float16 As[64][32];
    __shared__ _Float16 Bs[64][32];
    const int mt = blockIdx.x, ct = blockIdx.y;
    const int tid = threadIdx.x, wave = tid >> 6, lane = tid & 63;
    const int r = (ct * 64) / OUT_;
    const int o0 = (ct * 64) % OUT_;
    const float* Bg = W + (size_t)r * (F_ + REL_) * OUT_ + o0;
    const int m0 = mt * 64;
    const int lm = lane & 15, q = lane >> 4;
    f32x4 acc[4] = {};
    for (int k0 = 0; k0 < F_; k0 += 32) {
        {
            int seg = (tid & 3) * 8, m = tid >> 2;
            const float* src = feat + (size_t)(m0 + m) * F_ + k0 + seg;
#pragma unroll
            for (int j = 0; j < 8; ++j) As[m][seg + j] = (_Float16)src[j];
        }
        {
            int kk = tid >> 3, ns = (tid & 7) * 8;
            const float* src = Bg + (size_t)(k0 + kk) * OUT_ + ns;
#pragma unroll
            for (int j = 0; j < 8; ++j) Bs[ns + j][kk] = (_Float16)src[j];
        }
        __syncthreads();
        f16x8 a = *(const f16x8*)&As[wave * 16 + lm][q * 8];
#pragma unroll
        for (int c4 = 0; c4 < 4; ++c4) {
            f16x8 b = *(const f16x8*)&Bs[c4 * 16 + lm][q * 8];
            acc[c4] = __builtin_amdgcn_mfma_f32_16x16x32_f16(a, b, acc[c4], 0, 0, 0);
        }
        __syncthreads();
    }
#pragma unroll
    for (int c4 = 0; c4 < 4; ++c4)
#pragma unroll
        for (int g = 0; g < 4; ++g) {
            int row = wave * 16 + (lane >> 4) * 4 + g;
            int col = c4 * 16 + lm;
            float v = acc[c4][g] + cb[r * OUT_ + o0 + col];
            HWb[((size_t)r * B_ * N_ + m0 + row) * OUT_ + o0 + col] = (_Float16)v;
        }
}

__global__ __launch_bounds__(256) void agg_kernel(const float* __restrict__ A1,
                                                  const float* __restrict__ A2,
                                                  const _Float16* __restrict__ HWb,
                                                  const float* __restrict__ bias,
                                                  float* __restrict__ out) {
    __shared__ _Float16 As[64][32];
    __shared__ _Float16 Bs[64][32];
    const int b = blockIdx.z, nt = blockIdx.y, ot = blockIdx.x;
    const int tid = threadIdx.x, wave = tid >> 6, lane = tid & 63;
    const int n0 = nt * 64, o0 = ot * 64;
    const int lm = lane & 15, q = lane >> 4;
    const size_t rstride = (size_t)B_ * N_ * OUT_;
    f32x4 mx[4];
#pragma unroll
    for (int i = 0; i < 4; ++i) mx[i] = f32x4{-1e30f, -1e30f, -1e30f, -1e30f};
#pragma unroll 1
    for (int rr = 0; rr < 4; ++rr) {
        const float* Ag = ((rr & 1) ? A2 : A1) + (size_t)b * N_ * N_;
        const bool tr = (rr >= 2);
        const int r = (rr < 2) ? rr : rr + 1;
        const _Float16* Bg = HWb + (size_t)r * rstride + (size_t)b * N_ * OUT_ + o0;
        f32x4 acc[4] = {};
        for (int k0 = 0; k0 < N_; k0 += 32) {
            if (!tr) {
                int seg = (tid & 3) * 8, m = tid >> 2;
                const float* src = Ag + (size_t)(n0 + m) * N_ + k0 + seg;
#pragma unroll
                for (int j = 0; j < 8; ++j) As[m][seg + j] = (_Float16)src[j];
            } else {
                int kk = tid >> 3, ms = (tid & 7) * 8;
                const float* src = Ag + (size_t)(k0 + kk) * N_ + n0 + ms;
#pragma unroll
                for (int j = 0; j < 8; ++j) As[ms + j][kk] = (_Float16)src[j];
            }
            {
                int kk = tid >> 3, ns = (tid & 7) * 8;
                const _Float16* src = Bg + (size_t)(k0 + kk) * OUT_ + ns;
#pragma unroll
                for (int j = 0; j < 8; ++j) Bs[ns + j][kk] = src[j];
            }
            __syncthreads();
            f16x8 a = *(const f16x8*)&As[wave * 16 + lm][q * 8];
#pragma unroll
            for (int c4 = 0; c4 < 4; ++c4) {
                f16x8 bb = *(const f16x8*)&Bs[c4 * 16 + lm][q * 8];
                acc[c4] = __builtin_amdgcn_mfma_f32_16x16x32_f16(a, bb, acc[c4], 0, 0, 0);
            }
            __syncthreads();
        }
#pragma unroll
        for (int c4 = 0; c4 < 4; ++c4)
#pragma unroll
            for (int g = 0; g < 4; ++g) mx[c4][g] = fmaxf(mx[c4][g], acc[c4][g]);
    }
#pragma unroll
    for (int c4 = 0; c4 < 4; ++c4)
#pragma unroll
        for (int g = 0; g < 4; ++g) {
            int row = wave * 16 + (lane >> 4) * 4 + g;
            int col = c4 * 16 + lm;
            size_t pos = ((size_t)b * N_ + n0 + row) * OUT_ + o0 + col;
            float v = mx[c4][g];
            v = fmaxf(v, (float)HWb[2 * rstride + pos]);
            v = fmaxf(v, (float)HWb[5 * rstride + pos]);
            v = fmaxf(v, (float)HWb[6 * rstride + pos]);
            out[pos] = v + bias[((size_t)(n0 + row)) * OUT_ + o0 + col];
        }
}

// ========================================================================================
extern "C" void kernel_launch(void* const* d_in, const int* in_sizes, int n_in,
                              void* d_out, int out_size, void* d_ws, size_t ws_size,
                              hipStream_t stream) {
    const float* feat = (const float*)d_in[0];
    const float* A1   = (const float*)d_in[1];
    const float* A2   = (const float*)d_in[2];
    const float* W    = (const float*)d_in[3];
    const float* We   = (const float*)d_in[4];
    const float* bias = (const float*)d_in[5];
    float* out = (float*)d_out;

    // fast-path ws layout (bytes) — AHW 2 K-halves x 16 MB, total 65 MB
    const size_t OFF_CB   = 0;          //   8 KB
    const size_t OFF_WT   = 8192;       // 896 KB
    const size_t OFF_FE   = 1048576;    //   4 MB
    const size_t OFF_HWT  = 5242880;    //  16 MB
    const size_t OFF_HWN  = 22020096;   //  12 MB
    const size_t OFF_AHW  = 34603008;   //  32 MB (2 halves)
    const size_t WS_NEEDED = 68157440;

    if (ws_size >= WS_NEEDED) {
        float*    cbp = (float*)((char*)d_ws + OFF_CB);
        _Float16* WTp = (_Float16*)((char*)d_ws + OFF_WT);
        _Float16* Fe  = (_Float16*)((char*)d_ws + OFF_FE);
        _Float16* HWT = (_Float16*)((char*)d_ws + OFF_HWT);
        _Float16* HWN = (_Float16*)((char*)d_ws + OFF_HWN);
        _Float16* AHW = (_Float16*)((char*)d_ws + OFF_AHW);

        prep_kernel<<<2823, 256, 0, stream>>>(W, We, feat, cbp, WTp, Fe);
        hw7_kernel<<<896, 256, 0, stream>>>(Fe, WTp, cbp, HWT, HWN);
        p2_kernel<<<1024, 256, 0, stream>>>(A1, A2, HWT, AHW);
        max_kernel<<<1024, 256, 0, stream>>>(AHW, HWN, bias, out);
    } else {
        // round-1 fallback
        float* cb = (float*)d_ws;
        _Float16* HWb = (_Float16*)((char*)d_ws + 8192);
        cbias_kernel<<<7, 256, 0, stream>>>(W, We, cb);
        hw_kernel<<<dim3(128, 28), 256, 0, stream>>>(feat, W, cb, HWb);
        agg_kernel<<<dim3(4, 16, 8), 256, 0, stream>>>(A1, A2, HWb, bias, out);
    }
}